// Round 11
// baseline (277.631 us; speedup 1.0000x reference)
//
#include <hip/hip_runtime.h>
#include <math.h>

// R10 structure (row in registers, candidate Newton, NT load/store), occupancy
// pushed: 768-thread blocks, VPT=11 (44 data VGPRs), __launch_bounds__(768,6)
// -> 6 waves/SIMD = 24 waves/CU = 2 resident blocks/CU of 12 waves each
// (R10: 2x8). More waves in flight to fill the reduce/Newton bubbles of the
// neighbor block. VGPR cap ~85 at 6 waves/EU; est. need ~75 -> no spill.

constexpr int D       = 32000;
constexpr int NV4     = D / 4;          // 8000 float4 per row
constexpr int THREADS = 768;
constexpr int NWAVES  = THREADS / 64;   // 12 waves
constexpr int VPT     = 11;             // 768*11 = 8448 float4 slots >= 8000
constexpr int CAP     = 2048;           // candidate capacity

typedef float f32x4 __attribute__((ext_vector_type(4)));

__global__ __launch_bounds__(THREADS, 6)   // 6 waves/SIMD -> 2 blocks/CU
void sparsemax_768(const float* __restrict__ X, float* __restrict__ Y) {
    const int row  = blockIdx.x;
    const int tid  = threadIdx.x;
    const int wid  = tid >> 6;
    const int lane = tid & 63;

    const f32x4* xr = reinterpret_cast<const f32x4*>(X + (size_t)row * D);
    f32x4*       yr = reinterpret_cast<f32x4*>(Y + (size_t)row * D);

    __shared__ float sa[NWAVES];
    __shared__ float cval[CAP];
    __shared__ int   cidx[CAP];
    __shared__ int   cnt;

    if (tid == 0) cnt = 0;

    // ---- load the whole row into registers (coalesced, 16B/lane, NT) ----
    f32x4 r[VPT];
    #pragma unroll
    for (int j = 0; j < VPT; ++j) {
        const int idx = tid + j * THREADS;
        if (idx < NV4) {
            r[j] = __builtin_nontemporal_load(&xr[idx]);
        } else {
            r[j] = (f32x4){-INFINITY, -INFINITY, -INFINITY, -INFINITY};
        }
    }

    // ---- row max ----
    float m = -INFINITY;
    #pragma unroll
    for (int j = 0; j < VPT; ++j)
        m = fmaxf(m, fmaxf(fmaxf(r[j].x, r[j].y), fmaxf(r[j].z, r[j].w)));
    #pragma unroll
    for (int off = 32; off >= 1; off >>= 1)
        m = fmaxf(m, __shfl_xor(m, off, 64));
    if (lane == 0) sa[wid] = m;
    __syncthreads();                       // also orders cnt=0 vs atomics below
    float rowmax = sa[0];
    #pragma unroll
    for (int w = 1; w < NWAVES; ++w) rowmax = fmaxf(rowmax, sa[w]);

    // ---- collect candidates (value, index) with x > rowmax - 1 ----
    const float thresh = rowmax - 1.0f;
    #pragma unroll
    for (int j = 0; j < VPT; ++j) {
        const int base = (tid + j * THREADS) * 4;
        float v;
        v = r[j].x; if (v > thresh) { int i = atomicAdd(&cnt, 1); if (i < CAP) { cval[i] = v; cidx[i] = base + 0; } }
        v = r[j].y; if (v > thresh) { int i = atomicAdd(&cnt, 1); if (i < CAP) { cval[i] = v; cidx[i] = base + 1; } }
        v = r[j].z; if (v > thresh) { int i = atomicAdd(&cnt, 1); if (i < CAP) { cval[i] = v; cidx[i] = base + 2; } }
        v = r[j].w; if (v > thresh) { int i = atomicAdd(&cnt, 1); if (i < CAP) { cval[i] = v; cidx[i] = base + 3; } }
    }
    __syncthreads();
    const int K = cnt;

    float tau, inv;
    if (K <= CAP) {
        // ---- single-wave Newton over the candidate set ----
        __shared__ float s_tau, s_inv;
        if (wid == 0) {
            float t = thresh;
            for (int it = 0; it < 60; ++it) {
                float s = 0.0f, c = 0.0f;
                for (int i = lane; i < K; i += 64) {
                    const float v = cval[i] - t;
                    if (v > 0.0f) { s += v; c += 1.0f; }
                }
                #pragma unroll
                for (int off = 32; off >= 1; off >>= 1) {
                    s += __shfl_xor(s, off, 64);
                    c += __shfl_xor(c, off, 64);
                }
                const float f = s - 1.0f;
                if (f <= 1e-6f) break;
                const float nt = t + f / c;   // c >= 1 (rowmax is always active)
                if (nt == t) break;
                t = nt;
            }
            float s = 0.0f;
            for (int i = lane; i < K; i += 64) s += fmaxf(cval[i] - t, 0.0f);
            #pragma unroll
            for (int off = 32; off >= 1; off >>= 1) s += __shfl_xor(s, off, 64);
            if (lane == 0) { s_tau = t; s_inv = 1.0f / s; }
        }
        __syncthreads();
        tau = s_tau;
        inv = s_inv;
    } else {
        // ---- fallback: block-wide Newton over full register data ----
        __shared__ float fa[NWAVES], fb[NWAVES];
        tau = thresh;
        for (int it = 0; it < 60; ++it) {
            float s = 0.0f, c = 0.0f;
            #pragma unroll
            for (int j = 0; j < VPT; ++j) {
                float v;
                v = r[j].x - tau; if (v > 0.0f) { s += v; c += 1.0f; }
                v = r[j].y - tau; if (v > 0.0f) { s += v; c += 1.0f; }
                v = r[j].z - tau; if (v > 0.0f) { s += v; c += 1.0f; }
                v = r[j].w - tau; if (v > 0.0f) { s += v; c += 1.0f; }
            }
            #pragma unroll
            for (int off = 32; off >= 1; off >>= 1) {
                s += __shfl_xor(s, off, 64);
                c += __shfl_xor(c, off, 64);
            }
            __syncthreads();
            if (lane == 0) { fa[wid] = s; fb[wid] = c; }
            __syncthreads();
            float S = 0.0f, C = 0.0f;
            #pragma unroll
            for (int w = 0; w < NWAVES; ++w) { S += fa[w]; C += fb[w]; }
            const float f = S - 1.0f;
            if (f <= 1e-6f) break;
            const float nt = tau + f / C;
            if (nt == tau) break;
            tau = nt;
        }
        float s = 0.0f;
        #pragma unroll
        for (int j = 0; j < VPT; ++j) {
            s += fmaxf(r[j].x - tau, 0.0f);
            s += fmaxf(r[j].y - tau, 0.0f);
            s += fmaxf(r[j].z - tau, 0.0f);
            s += fmaxf(r[j].w - tau, 0.0f);
        }
        #pragma unroll
        for (int off = 32; off >= 1; off >>= 1) s += __shfl_xor(s, off, 64);
        __syncthreads();
        if (lane == 0) fa[wid] = s;
        __syncthreads();
        float S = 0.0f;
        #pragma unroll
        for (int w = 0; w < NWAVES; ++w) S += fa[w];
        inv = 1.0f / S;
    }

    // ---- write p = max(x - tau, 0) * inv, coalesced float4 burst (NT) ----
    #pragma unroll
    for (int j = 0; j < VPT; ++j) {
        const int idx = tid + j * THREADS;
        if (idx < NV4) {
            f32x4 o;
            o.x = fmaxf(r[j].x - tau, 0.0f) * inv;
            o.y = fmaxf(r[j].y - tau, 0.0f) * inv;
            o.z = fmaxf(r[j].z - tau, 0.0f) * inv;
            o.w = fmaxf(r[j].w - tau, 0.0f) * inv;
            __builtin_nontemporal_store(o, &yr[idx]);
        }
    }
}

extern "C" void kernel_launch(void* const* d_in, const int* in_sizes, int n_in,
                              void* d_out, int out_size, void* d_ws, size_t ws_size,
                              hipStream_t stream) {
    const float* X = (const float*)d_in[0];
    float*       Y = (float*)d_out;
    const int rows = in_sizes[0] / D;
    sparsemax_768<<<rows, THREADS, 0, stream>>>(X, Y);
}

// Round 12
// 197.832 us; speedup vs baseline: 1.4034x; 1.4034x over previous
//
#include <hip/hip_runtime.h>
#include <math.h>

// Two-phase sparsemax:
//  K1 (one block per HALF-row): load half -> local max -> candidates
//     {x > localmax-1} to workspace (superset of global candidates, since
//     rowmax >= localmax and tau >= rowmax-1) -> UNCONDITIONAL zero burst of
//     the half (branch-free store stream). 32 data VGPRs, lb(512,6): 3 blk/CU.
//  K2 (one wave per row): merge halves, Newton over the ~12 L2-hot ws
//     candidates, scatter nonzeros over the zeros. ~5 us.
// Both heavy streams stay in K1 (R3/R6: separate write passes lose); compute
// bubble per block shrinks 4x and resident blocks rise to 3/CU (R10: 2/CU).
// Fallbacks: ws too small -> proven R10 single-kernel; candidate overflow ->
// exact slow re-read path in K2 (never taken for Gaussian rows).

constexpr int D      = 32000;
constexpr int HALF   = D / 2;            // 16000 elems
constexpr int HV4    = HALF / 4;         // 4000 float4 per half
constexpr int T1     = 512;
constexpr int W1     = T1 / 64;          // 8 waves
constexpr int VPT1   = 8;                // 512*8 = 4096 >= 4000
constexpr int CAP_H  = 512;              // candidates per half in ws
// ws layout: hdr int2[nhalves] at 0; cands int2[nhalves*CAP_H] after 64KB.
constexpr size_t HDR_BYTES = 8192 * sizeof(int2);   // supports up to 8192 halves

typedef float f32x4 __attribute__((ext_vector_type(4)));

__global__ __launch_bounds__(T1, 6)
void k1_scan_zero(const float* __restrict__ X, float* __restrict__ Y,
                  int2* __restrict__ hdr, int2* __restrict__ cands) {
    const int hb   = blockIdx.x;          // half index
    const int row  = hb >> 1;
    const int half = hb & 1;
    const int tid  = threadIdx.x;
    const int wid  = tid >> 6;
    const int lane = tid & 63;

    const size_t base_elem = (size_t)row * D + (size_t)half * HALF;
    const f32x4* xr = reinterpret_cast<const f32x4*>(X + base_elem);
    f32x4*       yr = reinterpret_cast<f32x4*>(Y + base_elem);

    __shared__ float sa[W1];
    __shared__ int   cnt;
    if (tid == 0) cnt = 0;

    // ---- load half into registers ----
    f32x4 r[VPT1];
    #pragma unroll
    for (int j = 0; j < VPT1; ++j) {
        const int idx = tid + j * T1;
        if (idx < HV4) r[j] = __builtin_nontemporal_load(&xr[idx]);
        else           r[j] = (f32x4){-INFINITY, -INFINITY, -INFINITY, -INFINITY};
    }

    // ---- local max ----
    float m = -INFINITY;
    #pragma unroll
    for (int j = 0; j < VPT1; ++j)
        m = fmaxf(m, fmaxf(fmaxf(r[j].x, r[j].y), fmaxf(r[j].z, r[j].w)));
    #pragma unroll
    for (int off = 32; off >= 1; off >>= 1)
        m = fmaxf(m, __shfl_xor(m, off, 64));
    if (lane == 0) sa[wid] = m;
    __syncthreads();
    float lmax = sa[0];
    #pragma unroll
    for (int w = 1; w < W1; ++w) lmax = fmaxf(lmax, sa[w]);
    const float thresh = lmax - 1.0f;

    // ---- collect candidates to ws (few; direct global stores) ----
    int2* my_cands = cands + (size_t)hb * CAP_H;
    #pragma unroll
    for (int j = 0; j < VPT1; ++j) {
        const int idx = tid + j * T1;
        if (idx < HV4) {
            const int ebase = half * HALF + idx * 4;   // element idx within row
            const f32x4 v = r[j];
            if (v.x > thresh) { int i = atomicAdd(&cnt, 1); if (i < CAP_H) my_cands[i] = make_int2(__float_as_int(v.x), ebase + 0); }
            if (v.y > thresh) { int i = atomicAdd(&cnt, 1); if (i < CAP_H) my_cands[i] = make_int2(__float_as_int(v.y), ebase + 1); }
            if (v.z > thresh) { int i = atomicAdd(&cnt, 1); if (i < CAP_H) my_cands[i] = make_int2(__float_as_int(v.z), ebase + 2); }
            if (v.w > thresh) { int i = atomicAdd(&cnt, 1); if (i < CAP_H) my_cands[i] = make_int2(__float_as_int(v.w), ebase + 3); }
        }
    }

    // ---- unconditional zero burst of this half ----
    const f32x4 z = (f32x4){0.0f, 0.0f, 0.0f, 0.0f};
    #pragma unroll
    for (int j = 0; j < VPT1; ++j) {
        const int idx = tid + j * T1;
        if (idx < HV4) __builtin_nontemporal_store(z, &yr[idx]);
    }

    __syncthreads();
    if (tid == 0) hdr[hb] = make_int2(cnt, __float_as_int(lmax));
}

__global__ __launch_bounds__(64)
void k2_newton_scatter(const float* __restrict__ X, float* __restrict__ Y,
                       const int2* __restrict__ hdr, const int2* __restrict__ cands) {
    const int row  = blockIdx.x;
    const int lane = threadIdx.x;
    const int h0 = row * 2, h1 = h0 + 1;

    const int2 a = hdr[h0], b = hdr[h1];
    const int   c0 = a.x, c1 = b.x;
    const float rowmax = fmaxf(__int_as_float(a.y), __int_as_float(b.y));
    const float thresh = rowmax - 1.0f;

    if (c0 <= CAP_H && c1 <= CAP_H) {
        const int K = c0 + c1;
        const int2* p0 = cands + (size_t)h0 * CAP_H;
        const int2* p1 = cands + (size_t)h1 * CAP_H;
        // Newton (candidates are a superset; elements <= thresh contribute 0)
        float t = thresh;
        for (int it = 0; it < 60; ++it) {
            float s = 0.0f, c = 0.0f;
            for (int i = lane; i < K; i += 64) {
                const int2 e = (i < c0) ? p0[i] : p1[i - c0];
                const float v = __int_as_float(e.x) - t;
                if (v > 0.0f) { s += v; c += 1.0f; }
            }
            #pragma unroll
            for (int off = 32; off >= 1; off >>= 1) {
                s += __shfl_xor(s, off, 64);
                c += __shfl_xor(c, off, 64);
            }
            const float f = s - 1.0f;
            if (f <= 1e-6f) break;
            const float nt = t + f / c;       // c >= 1 (rowmax stays active)
            if (nt == t) break;
            t = nt;
        }
        float s = 0.0f;
        for (int i = lane; i < K; i += 64) {
            const int2 e = (i < c0) ? p0[i] : p1[i - c0];
            s += fmaxf(__int_as_float(e.x) - t, 0.0f);
        }
        #pragma unroll
        for (int off = 32; off >= 1; off >>= 1) s += __shfl_xor(s, off, 64);
        const float inv = 1.0f / s;
        float* yrow = Y + (size_t)row * D;
        for (int i = lane; i < K; i += 64) {
            const int2 e = (i < c0) ? p0[i] : p1[i - c0];
            yrow[e.y] = fmaxf(__int_as_float(e.x) - t, 0.0f) * inv; // 0 for inactive: still correct
        }
    } else {
        // ---- exact fallback (never taken for Gaussian): stream the row ----
        const float* xrow = X + (size_t)row * D;
        float t = thresh;
        for (int it = 0; it < 60; ++it) {
            float s = 0.0f, c = 0.0f;
            for (int i = lane; i < D; i += 64) {
                const float v = xrow[i] - t;
                if (v > 0.0f) { s += v; c += 1.0f; }
            }
            #pragma unroll
            for (int off = 32; off >= 1; off >>= 1) {
                s += __shfl_xor(s, off, 64);
                c += __shfl_xor(c, off, 64);
            }
            const float f = s - 1.0f;
            if (f <= 1e-6f) break;
            const float nt = t + f / c;
            if (nt == t) break;
            t = nt;
        }
        float s = 0.0f;
        for (int i = lane; i < D; i += 64) s += fmaxf(xrow[i] - t, 0.0f);
        #pragma unroll
        for (int off = 32; off >= 1; off >>= 1) s += __shfl_xor(s, off, 64);
        const float inv = 1.0f / s;
        float* yrow = Y + (size_t)row * D;
        for (int i = lane; i < D; i += 64) {
            const float p = fmaxf(xrow[i] - t, 0.0f);
            if (p > 0.0f) yrow[i] = p * inv;
        }
    }
}

// ---------------- proven R10 single-kernel fallback (ws too small) ----------
constexpr int NV4   = D / 4;
constexpr int TF    = 512;
constexpr int WF    = TF / 64;
constexpr int VPTF  = 16;
constexpr int CAPF  = 2048;

__global__ __launch_bounds__(TF, 4)
void sparsemax_2blk(const float* __restrict__ X, float* __restrict__ Y) {
    const int row  = blockIdx.x;
    const int tid  = threadIdx.x;
    const int wid  = tid >> 6;
    const int lane = tid & 63;

    const f32x4* xr = reinterpret_cast<const f32x4*>(X + (size_t)row * D);
    f32x4*       yr = reinterpret_cast<f32x4*>(Y + (size_t)row * D);

    __shared__ float sa[WF];
    __shared__ float cval[CAPF];
    __shared__ int   cidx[CAPF];
    __shared__ int   cnt;
    if (tid == 0) cnt = 0;

    f32x4 r[VPTF];
    #pragma unroll
    for (int j = 0; j < VPTF; ++j) {
        const int idx = tid + j * TF;
        if (idx < NV4) r[j] = __builtin_nontemporal_load(&xr[idx]);
        else           r[j] = (f32x4){-INFINITY, -INFINITY, -INFINITY, -INFINITY};
    }
    float m = -INFINITY;
    #pragma unroll
    for (int j = 0; j < VPTF; ++j)
        m = fmaxf(m, fmaxf(fmaxf(r[j].x, r[j].y), fmaxf(r[j].z, r[j].w)));
    #pragma unroll
    for (int off = 32; off >= 1; off >>= 1) m = fmaxf(m, __shfl_xor(m, off, 64));
    if (lane == 0) sa[wid] = m;
    __syncthreads();
    float rowmax = sa[0];
    #pragma unroll
    for (int w = 1; w < WF; ++w) rowmax = fmaxf(rowmax, sa[w]);
    const float thresh = rowmax - 1.0f;
    #pragma unroll
    for (int j = 0; j < VPTF; ++j) {
        const int base = (tid + j * TF) * 4;
        float v;
        v = r[j].x; if (v > thresh) { int i = atomicAdd(&cnt, 1); if (i < CAPF) { cval[i] = v; cidx[i] = base + 0; } }
        v = r[j].y; if (v > thresh) { int i = atomicAdd(&cnt, 1); if (i < CAPF) { cval[i] = v; cidx[i] = base + 1; } }
        v = r[j].z; if (v > thresh) { int i = atomicAdd(&cnt, 1); if (i < CAPF) { cval[i] = v; cidx[i] = base + 2; } }
        v = r[j].w; if (v > thresh) { int i = atomicAdd(&cnt, 1); if (i < CAPF) { cval[i] = v; cidx[i] = base + 3; } }
    }
    __syncthreads();
    const int K = cnt;
    float tau, inv;
    if (K <= CAPF) {
        __shared__ float s_tau, s_inv;
        if (wid == 0) {
            float t = thresh;
            for (int it = 0; it < 60; ++it) {
                float s = 0.0f, c = 0.0f;
                for (int i = lane; i < K; i += 64) {
                    const float v = cval[i] - t;
                    if (v > 0.0f) { s += v; c += 1.0f; }
                }
                #pragma unroll
                for (int off = 32; off >= 1; off >>= 1) {
                    s += __shfl_xor(s, off, 64);
                    c += __shfl_xor(c, off, 64);
                }
                const float f = s - 1.0f;
                if (f <= 1e-6f) break;
                const float nt = t + f / c;
                if (nt == t) break;
                t = nt;
            }
            float s = 0.0f;
            for (int i = lane; i < K; i += 64) s += fmaxf(cval[i] - t, 0.0f);
            #pragma unroll
            for (int off = 32; off >= 1; off >>= 1) s += __shfl_xor(s, off, 64);
            if (lane == 0) { s_tau = t; s_inv = 1.0f / s; }
        }
        __syncthreads();
        tau = s_tau; inv = s_inv;
    } else {
        __shared__ float fa[WF], fb[WF];
        tau = thresh;
        for (int it = 0; it < 60; ++it) {
            float s = 0.0f, c = 0.0f;
            #pragma unroll
            for (int j = 0; j < VPTF; ++j) {
                float v;
                v = r[j].x - tau; if (v > 0.0f) { s += v; c += 1.0f; }
                v = r[j].y - tau; if (v > 0.0f) { s += v; c += 1.0f; }
                v = r[j].z - tau; if (v > 0.0f) { s += v; c += 1.0f; }
                v = r[j].w - tau; if (v > 0.0f) { s += v; c += 1.0f; }
            }
            #pragma unroll
            for (int off = 32; off >= 1; off >>= 1) {
                s += __shfl_xor(s, off, 64);
                c += __shfl_xor(c, off, 64);
            }
            __syncthreads();
            if (lane == 0) { fa[wid] = s; fb[wid] = c; }
            __syncthreads();
            float S = 0.0f, C = 0.0f;
            #pragma unroll
            for (int w = 0; w < WF; ++w) { S += fa[w]; C += fb[w]; }
            const float f = S - 1.0f;
            if (f <= 1e-6f) break;
            const float nt = tau + f / C;
            if (nt == tau) break;
            tau = nt;
        }
        float s = 0.0f;
        #pragma unroll
        for (int j = 0; j < VPTF; ++j) {
            s += fmaxf(r[j].x - tau, 0.0f);
            s += fmaxf(r[j].y - tau, 0.0f);
            s += fmaxf(r[j].z - tau, 0.0f);
            s += fmaxf(r[j].w - tau, 0.0f);
        }
        #pragma unroll
        for (int off = 32; off >= 1; off >>= 1) s += __shfl_xor(s, off, 64);
        __syncthreads();
        if (lane == 0) fa[wid] = s;
        __syncthreads();
        float S = 0.0f;
        #pragma unroll
        for (int w = 0; w < WF; ++w) S += fa[w];
        inv = 1.0f / S;
    }
    #pragma unroll
    for (int j = 0; j < VPTF; ++j) {
        const int idx = tid + j * TF;
        if (idx < NV4) {
            f32x4 o;
            o.x = fmaxf(r[j].x - tau, 0.0f) * inv;
            o.y = fmaxf(r[j].y - tau, 0.0f) * inv;
            o.z = fmaxf(r[j].z - tau, 0.0f) * inv;
            o.w = fmaxf(r[j].w - tau, 0.0f) * inv;
            __builtin_nontemporal_store(o, &yr[idx]);
        }
    }
}

extern "C" void kernel_launch(void* const* d_in, const int* in_sizes, int n_in,
                              void* d_out, int out_size, void* d_ws, size_t ws_size,
                              hipStream_t stream) {
    const float* X = (const float*)d_in[0];
    float*       Y = (float*)d_out;
    const int rows    = in_sizes[0] / D;
    const int nhalves = rows * 2;
    const size_t need = HDR_BYTES + (size_t)nhalves * CAP_H * sizeof(int2);

    if (ws_size >= need && nhalves <= 8192) {
        int2* hdr   = (int2*)d_ws;
        int2* cands = (int2*)((char*)d_ws + HDR_BYTES);
        k1_scan_zero<<<nhalves, T1, 0, stream>>>(X, Y, hdr, cands);
        k2_newton_scatter<<<rows, 64, 0, stream>>>(X, Y, hdr, cands);
    } else {
        sparsemax_2blk<<<rows, TF, 0, stream>>>(X, Y);
    }
}

// Round 13
// 190.618 us; speedup vs baseline: 1.4565x; 1.0378x over previous
//
#include <hip/hip_runtime.h>
#include <math.h>

// FINAL (revert to R10, best measured: 191.4 us = 87% of the 6.29 TB/s
// mixed-stream copy ceiling on 1.07 GB of traffic).
// Structure: one 512-thread block per row, row fully in registers (VPT=16),
// __launch_bounds__(512,4) -> 2 resident blocks/CU so one block's load/store
// bursts overlap the other's reduce/Newton bubble. Rowmax -> candidate set
// {x > rowmax-1} (tau only increases from tau0 = rowmax-1) -> single-wave
// Newton on the tiny LDS set -> full-row NT write burst.
// Ledger: separate write pass (R3/R6/R12) loses; interleaved stores (R4)
// loses; store-loop branches (R7) lose; NT policy (R9) neutral; occupancy
// beyond 2 blk/CU (R5/R11/R12) loses to spills/launches.
// Fallback (K > CAP, adversarial only): block-wide Newton over registers.

constexpr int D       = 32000;
constexpr int NV4     = D / 4;          // 8000 float4 per row
constexpr int THREADS = 512;
constexpr int NWAVES  = THREADS / 64;   // 8 waves
constexpr int VPT     = 16;             // 512*16 = 8192 float4 slots >= 8000
constexpr int CAP     = 2048;           // candidate capacity

typedef float f32x4 __attribute__((ext_vector_type(4)));

__global__ __launch_bounds__(THREADS, 4)   // 4 waves/SIMD = 2 blocks/CU
void sparsemax_2blk(const float* __restrict__ X, float* __restrict__ Y) {
    const int row  = blockIdx.x;
    const int tid  = threadIdx.x;
    const int wid  = tid >> 6;
    const int lane = tid & 63;

    const f32x4* xr = reinterpret_cast<const f32x4*>(X + (size_t)row * D);
    f32x4*       yr = reinterpret_cast<f32x4*>(Y + (size_t)row * D);

    __shared__ float sa[NWAVES];
    __shared__ float cval[CAP];
    __shared__ int   cidx[CAP];
    __shared__ int   cnt;

    if (tid == 0) cnt = 0;

    // ---- load the whole row into registers (coalesced, 16B/lane, NT) ----
    f32x4 r[VPT];
    #pragma unroll
    for (int j = 0; j < VPT; ++j) {
        const int idx = tid + j * THREADS;
        if (idx < NV4) {
            r[j] = __builtin_nontemporal_load(&xr[idx]);
        } else {
            r[j] = (f32x4){-INFINITY, -INFINITY, -INFINITY, -INFINITY};
        }
    }

    // ---- row max ----
    float m = -INFINITY;
    #pragma unroll
    for (int j = 0; j < VPT; ++j)
        m = fmaxf(m, fmaxf(fmaxf(r[j].x, r[j].y), fmaxf(r[j].z, r[j].w)));
    #pragma unroll
    for (int off = 32; off >= 1; off >>= 1)
        m = fmaxf(m, __shfl_xor(m, off, 64));
    if (lane == 0) sa[wid] = m;
    __syncthreads();                       // also orders cnt=0 vs atomics below
    float rowmax = sa[0];
    #pragma unroll
    for (int w = 1; w < NWAVES; ++w) rowmax = fmaxf(rowmax, sa[w]);

    // ---- collect candidates (value, index) with x > rowmax - 1 ----
    const float thresh = rowmax - 1.0f;
    #pragma unroll
    for (int j = 0; j < VPT; ++j) {
        const int base = (tid + j * THREADS) * 4;
        float v;
        v = r[j].x; if (v > thresh) { int i = atomicAdd(&cnt, 1); if (i < CAP) { cval[i] = v; cidx[i] = base + 0; } }
        v = r[j].y; if (v > thresh) { int i = atomicAdd(&cnt, 1); if (i < CAP) { cval[i] = v; cidx[i] = base + 1; } }
        v = r[j].z; if (v > thresh) { int i = atomicAdd(&cnt, 1); if (i < CAP) { cval[i] = v; cidx[i] = base + 2; } }
        v = r[j].w; if (v > thresh) { int i = atomicAdd(&cnt, 1); if (i < CAP) { cval[i] = v; cidx[i] = base + 3; } }
    }
    __syncthreads();
    const int K = cnt;

    float tau, inv;
    if (K <= CAP) {
        // ---- single-wave Newton over the candidate set ----
        __shared__ float s_tau, s_inv;
        if (wid == 0) {
            float t = thresh;
            for (int it = 0; it < 60; ++it) {
                float s = 0.0f, c = 0.0f;
                for (int i = lane; i < K; i += 64) {
                    const float v = cval[i] - t;
                    if (v > 0.0f) { s += v; c += 1.0f; }
                }
                #pragma unroll
                for (int off = 32; off >= 1; off >>= 1) {
                    s += __shfl_xor(s, off, 64);
                    c += __shfl_xor(c, off, 64);
                }
                const float f = s - 1.0f;
                if (f <= 1e-6f) break;
                const float nt = t + f / c;   // c >= 1 (rowmax is always active)
                if (nt == t) break;
                t = nt;
            }
            float s = 0.0f;
            for (int i = lane; i < K; i += 64) s += fmaxf(cval[i] - t, 0.0f);
            #pragma unroll
            for (int off = 32; off >= 1; off >>= 1) s += __shfl_xor(s, off, 64);
            if (lane == 0) { s_tau = t; s_inv = 1.0f / s; }
        }
        __syncthreads();
        tau = s_tau;
        inv = s_inv;
    } else {
        // ---- fallback: block-wide Newton over full register data ----
        __shared__ float fa[NWAVES], fb[NWAVES];
        tau = thresh;
        for (int it = 0; it < 60; ++it) {
            float s = 0.0f, c = 0.0f;
            #pragma unroll
            for (int j = 0; j < VPT; ++j) {
                float v;
                v = r[j].x - tau; if (v > 0.0f) { s += v; c += 1.0f; }
                v = r[j].y - tau; if (v > 0.0f) { s += v; c += 1.0f; }
                v = r[j].z - tau; if (v > 0.0f) { s += v; c += 1.0f; }
                v = r[j].w - tau; if (v > 0.0f) { s += v; c += 1.0f; }
            }
            #pragma unroll
            for (int off = 32; off >= 1; off >>= 1) {
                s += __shfl_xor(s, off, 64);
                c += __shfl_xor(c, off, 64);
            }
            __syncthreads();
            if (lane == 0) { fa[wid] = s; fb[wid] = c; }
            __syncthreads();
            float S = 0.0f, C = 0.0f;
            #pragma unroll
            for (int w = 0; w < NWAVES; ++w) { S += fa[w]; C += fb[w]; }
            const float f = S - 1.0f;
            if (f <= 1e-6f) break;
            const float nt = tau + f / C;
            if (nt == tau) break;
            tau = nt;
        }
        float s = 0.0f;
        #pragma unroll
        for (int j = 0; j < VPT; ++j) {
            s += fmaxf(r[j].x - tau, 0.0f);
            s += fmaxf(r[j].y - tau, 0.0f);
            s += fmaxf(r[j].z - tau, 0.0f);
            s += fmaxf(r[j].w - tau, 0.0f);
        }
        #pragma unroll
        for (int off = 32; off >= 1; off >>= 1) s += __shfl_xor(s, off, 64);
        __syncthreads();
        if (lane == 0) fa[wid] = s;
        __syncthreads();
        float S = 0.0f;
        #pragma unroll
        for (int w = 0; w < NWAVES; ++w) S += fa[w];
        inv = 1.0f / S;
    }

    // ---- write p = max(x - tau, 0) * inv, coalesced float4 burst (NT) ----
    #pragma unroll
    for (int j = 0; j < VPT; ++j) {
        const int idx = tid + j * THREADS;
        if (idx < NV4) {
            f32x4 o;
            o.x = fmaxf(r[j].x - tau, 0.0f) * inv;
            o.y = fmaxf(r[j].y - tau, 0.0f) * inv;
            o.z = fmaxf(r[j].z - tau, 0.0f) * inv;
            o.w = fmaxf(r[j].w - tau, 0.0f) * inv;
            __builtin_nontemporal_store(o, &yr[idx]);
        }
    }
}

extern "C" void kernel_launch(void* const* d_in, const int* in_sizes, int n_in,
                              void* d_out, int out_size, void* d_ws, size_t ws_size,
                              hipStream_t stream) {
    const float* X = (const float*)d_in[0];
    float*       Y = (float*)d_out;
    const int rows = in_sizes[0] / D;
    sparsemax_2blk<<<rows, THREADS, 0, stream>>>(X, Y);
}